// Round 1
// baseline (4993.988 us; speedup 1.0000x reference)
//
#include <hip/hip_runtime.h>

typedef __attribute__((ext_vector_type(8))) short bf16x8;
typedef __attribute__((ext_vector_type(4))) float f32x4;
typedef __attribute__((ext_vector_type(4))) unsigned short us4;

__device__ __forceinline__ float b2f(unsigned short h) {
  union { unsigned int u; float f; } v; v.u = ((unsigned int)h) << 16; return v.f;
}
__device__ __forceinline__ unsigned short f2b(float f) {
  union { float f; unsigned int u; } v; v.f = f;
  unsigned int r = v.u + 0x7fffu + ((v.u >> 16) & 1u);
  return (unsigned short)(r >> 16);
}

// ---------------- fp32 -> bf16 bulk convert ----------------
__global__ void f2b_kernel(const float* __restrict__ in, unsigned short* __restrict__ out, int n4) {
  int i = blockIdx.x * blockDim.x + threadIdx.x;
  int stride = gridDim.x * blockDim.x;
  for (; i < n4; i += stride) {
    float4 v = reinterpret_cast<const float4*>(in)[i];
    us4 o;
    o.x = f2b(v.x); o.y = f2b(v.y); o.z = f2b(v.z); o.w = f2b(v.w);
    reinterpret_cast<us4*>(out)[i] = o;
  }
}

// ---------------- input embeddings (small K: 16/64), VALU ----------------
__global__ void embed_kernel(const float* __restrict__ in, const float* __restrict__ w,
                             const float* __restrict__ b, unsigned short* __restrict__ out,
                             int M, int K) {
  long total = (long)M * 128;
  long i = (long)blockIdx.x * blockDim.x + threadIdx.x;
  long stride = (long)gridDim.x * blockDim.x;
  for (; i < total; i += stride) {
    int row = (int)(i >> 7), col = (int)(i & 127);
    const float* ir = in + (long)row * K;
    const float* wr = w + (long)col * K;
    float s = b[col];
    for (int k = 0; k < K; ++k) s += ir[k] * wr[k];
    out[i] = f2b(s);
  }
}

// ---------------- main MFMA gather-GEMM ----------------
// X[M, nsrc*128] implicit: source si supplies k in [si*128,(si+1)*128),
// row index per source: kind 0 = direct row, 1 = send[row], 2 = rec[row].
// W: bf16 [128][nsrc*128] row-major (out-major, _lin's w layout).
// scatter=1: atomicAdd (acc+bias) into outF[rec[row]*128+col]
// scatter=0: write bf16 to outB[row], plus fp32 to outF if non-null.
__launch_bounds__(256, 2)
__global__ void gemm_mp(int M, int nsrc, int kinds, int scatter,
                        const unsigned short* __restrict__ sp0, const unsigned short* __restrict__ sp1,
                        const unsigned short* __restrict__ sp2, const unsigned short* __restrict__ sp3,
                        const unsigned short* __restrict__ sp4,
                        const int* __restrict__ send, const int* __restrict__ rec,
                        const unsigned short* __restrict__ Wb, const float* __restrict__ bias,
                        unsigned short* __restrict__ outB, float* __restrict__ outF) {
  __shared__ __align__(16) unsigned short ldsW[8 * 64 * 8];  // 8KB, fragment order [ntile][lane][8]
  const int tid = threadIdx.x;
  const int wid = tid >> 6, lane = tid & 63;
  const int K = nsrc * 128;
  const long rowBase = (long)blockIdx.x * 256 + wid * 64;
  const int lq = lane >> 4;  // 0..3
  const int lr = lane & 15;  // 0..15

  int rowD[4], idxS[4], idxR[4];
#pragma unroll
  for (int am = 0; am < 4; ++am) {
    long e = rowBase + am * 16 + lr;
    if (e >= M) e = M - 1;
    rowD[am] = (int)e;
    idxS[am] = send ? send[e] : (int)e;
    idxR[am] = rec ? rec[e] : (int)e;
  }

  f32x4 acc[4][8];
#pragma unroll
  for (int i = 0; i < 4; ++i)
#pragma unroll
    for (int j = 0; j < 8; ++j) acc[i][j] = 0.f;

  for (int si = 0; si < nsrc; ++si) {
    const unsigned short* sp = (si == 0) ? sp0 : (si == 1) ? sp1 : (si == 2) ? sp2 : (si == 3) ? sp3 : sp4;
    const int kd = (kinds >> (si * 4)) & 15;
#pragma unroll
    for (int sub = 0; sub < 4; ++sub) {
      const int k0 = si * 128 + sub * 32;
      __syncthreads();  // protect previous iteration's LDS reads (WAR)
      // stage W chunk [32k x 128n] into LDS in b-fragment order
#pragma unroll
      for (int it = 0; it < 2; ++it) {
        int idx = tid + it * 256;
        int t = idx >> 6, l = idx & 63;
        int n = t * 16 + (l & 15);
        int kk = k0 + ((l >> 4) * 8);
        *reinterpret_cast<bf16x8*>(&ldsW[idx * 8]) =
            *reinterpret_cast<const bf16x8*>(&Wb[(long)n * K + kk]);
      }
      __syncthreads();
      const int koff = sub * 32 + lq * 8;  // within source's 128-wide row
      bf16x8 a[4];
#pragma unroll
      for (int am = 0; am < 4; ++am) {
        int ridx = (kd == 0) ? rowD[am] : (kd == 1) ? idxS[am] : idxR[am];
        a[am] = *reinterpret_cast<const bf16x8*>(&sp[(long)ridx * 128 + koff]);
      }
#pragma unroll
      for (int n = 0; n < 8; ++n) {
        bf16x8 b = *reinterpret_cast<const bf16x8*>(&ldsW[(n * 64 + lane) * 8]);
#pragma unroll
        for (int am = 0; am < 4; ++am)
          acc[am][n] = __builtin_amdgcn_mfma_f32_16x16x32_bf16(a[am], b, acc[am][n], 0, 0, 0);
      }
    }
  }

  float bv[8];
#pragma unroll
  for (int n = 0; n < 8; ++n) bv[n] = bias[n * 16 + lr];

  // C layout (16x16x32 bf16): col = lane&15, row = (lane>>4)*4 + reg
  if (scatter) {
#pragma unroll
    for (int am = 0; am < 4; ++am) {
#pragma unroll
      for (int r = 0; r < 4; ++r) {
        long e = rowBase + am * 16 + lq * 4 + r;
        if (e < M) {
          int node = rec[e];
          float* dst = outF + (long)node * 128 + lr;
#pragma unroll
          for (int n = 0; n < 8; ++n) unsafeAtomicAdd(dst + n * 16, acc[am][n][r] + bv[n]);
        }
      }
    }
  } else {
#pragma unroll
    for (int am = 0; am < 4; ++am) {
#pragma unroll
      for (int r = 0; r < 4; ++r) {
        long row = rowBase + am * 16 + lq * 4 + r;
        if (row < M) {
#pragma unroll
          for (int n = 0; n < 8; ++n) {
            float v = acc[am][n][r] + bv[n];
            outB[row * 128 + n * 16 + lr] = f2b(v);
            if (outF) outF[row * 128 + n * 16 + lr] = v;
          }
        }
      }
    }
  }
}

// ---------------- per-graph aggregation (batch is sorted) ----------------
__global__ void readout_agg(const unsigned short* __restrict__ h, const unsigned short* __restrict__ p,
                            const int* __restrict__ batch, float* __restrict__ hep, int N) {
  int col = threadIdx.x & 127;
  int which = threadIdx.x >> 7;  // 0 -> h part, 1 -> p part
  const unsigned short* src = which ? p : h;
  int n0 = blockIdx.x * 128;
  int n1 = n0 + 128; if (n1 > N) n1 = N;
  float sum = 0.f; int curg = -1;
  for (int n = n0; n < n1; ++n) {
    int g = batch[n];
    if (g != curg) {
      if (curg >= 0) unsafeAtomicAdd(&hep[(long)curg * 256 + which * 128 + col], sum);
      curg = g; sum = 0.f;
    }
    sum += b2f(src[(long)n * 128 + col]);
  }
  if (curg >= 0) unsafeAtomicAdd(&hep[(long)curg * 256 + which * 128 + col], sum);
}

// ---------------- readout MLP: one block per graph ----------------
__global__ void mlp_kernel(const float* __restrict__ hep,
                           const float* __restrict__ r1w, const float* __restrict__ r1b,
                           const float* __restrict__ r2w, const float* __restrict__ r2b,
                           const float* __restrict__ r3w, const float* __restrict__ r3b,
                           float* __restrict__ out) {
  int g = blockIdx.x, t = threadIdx.x;  // 128 threads
  __shared__ float x[256];
  __shared__ float y[128];
  __shared__ float z[64];
  x[t] = hep[(long)g * 256 + t];
  x[t + 128] = hep[(long)g * 256 + 128 + t];
  __syncthreads();
  float s = r1b[t];
  for (int k = 0; k < 256; ++k) s += r1w[t * 256 + k] * x[k];
  y[t] = fmaxf(s, 0.f);
  __syncthreads();
  if (t < 64) {
    float s2 = r2b[t];
    for (int k = 0; k < 128; ++k) s2 += r2w[t * 128 + k] * y[k];
    z[t] = fmaxf(s2, 0.f);
  }
  __syncthreads();
  if (t == 0) {
    float s3 = r3b[0];
    for (int k = 0; k < 64; ++k) s3 += r3w[k] * z[k];
    out[g] = s3;
  }
}

extern "C" void kernel_launch(void* const* d_in, const int* in_sizes, int n_in,
                              void* d_out, int out_size, void* d_ws, size_t ws_size,
                              hipStream_t stream) {
  const float* h_in = (const float*)d_in[0];
  const float* e_in = (const float*)d_in[1];
  const float* p_in = (const float*)d_in[2];
  const int* ei = (const int*)d_in[3];
  const int* batch = (const int*)d_in[4];
  const float* he_w = (const float*)d_in[5];  const float* he_b = (const float*)d_in[6];
  const float* ee_w = (const float*)d_in[7];  const float* ee_b = (const float*)d_in[8];
  const float* pe_w = (const float*)d_in[9];  const float* pe_b = (const float*)d_in[10];
  const float* hu_w = (const float*)d_in[11]; const float* hu_b = (const float*)d_in[12];
  const float* eu_w = (const float*)d_in[13]; const float* eu_b = (const float*)d_in[14];
  const float* pu_w = (const float*)d_in[15]; const float* pu_b = (const float*)d_in[16];
  const float* hg_w = (const float*)d_in[17]; const float* hg_b = (const float*)d_in[18];
  const float* pg_w = (const float*)d_in[19]; const float* pg_b = (const float*)d_in[20];
  const float* r1w = (const float*)d_in[21];  const float* r1b = (const float*)d_in[22];
  const float* r2w = (const float*)d_in[23];  const float* r2b = (const float*)d_in[24];
  const float* r3w = (const float*)d_in[25];  const float* r3b = (const float*)d_in[26];

  const int N = 50000, E = 400000, G = 256;
  const int* send = ei;
  const int* rec = ei + E;

  char* ws = (char*)d_ws;
  size_t off = 0;
  auto alloc = [&](size_t bytes) {
    void* pp = ws + off;
    off += (bytes + 255) & ~(size_t)255;
    return pp;
  };
  unsigned short* hB = (unsigned short*)alloc((size_t)N * 128 * 2);
  unsigned short* pB = (unsigned short*)alloc((size_t)N * 128 * 2);
  unsigned short* eB = (unsigned short*)alloc((size_t)E * 128 * 2);
  float* aggF = (float*)alloc((size_t)N * 128 * 4);
  unsigned short* aggB = (unsigned short*)alloc((size_t)N * 128 * 2);
  float* hep = (float*)alloc((size_t)G * 256 * 4);
  unsigned short* w_he = (unsigned short*)alloc((size_t)128 * 64 * 2);
  unsigned short* w_ee = (unsigned short*)alloc((size_t)128 * 16 * 2);
  unsigned short* w_pe = (unsigned short*)alloc((size_t)128 * 16 * 2);
  unsigned short* w_hu = (unsigned short*)alloc((size_t)4 * 128 * 640 * 2);
  unsigned short* w_eu = (unsigned short*)alloc((size_t)4 * 128 * 384 * 2);
  unsigned short* w_pu = (unsigned short*)alloc((size_t)4 * 128 * 384 * 2);
  unsigned short* w_hg = (unsigned short*)alloc((size_t)4 * 128 * 256 * 2);
  unsigned short* w_pg = (unsigned short*)alloc((size_t)4 * 128 * 256 * 2);
  (void)ws_size; (void)n_in; (void)in_sizes; (void)out_size;

  auto conv = [&](const float* s, unsigned short* dst, int n) {
    int n4 = n / 4;
    int grid = (n4 + 255) / 256; if (grid > 2048) grid = 2048;
    f2b_kernel<<<grid, 256, 0, stream>>>(s, dst, n4);
  };
  conv(he_w, w_he, 128 * 64);
  conv(ee_w, w_ee, 128 * 16);
  conv(pe_w, w_pe, 128 * 16);
  conv(hu_w, w_hu, 4 * 128 * 640);
  conv(eu_w, w_eu, 4 * 128 * 384);
  conv(pu_w, w_pu, 4 * 128 * 384);
  conv(hg_w, w_hg, 4 * 128 * 256);
  conv(pg_w, w_pg, 4 * 128 * 256);

  embed_kernel<<<2048, 256, 0, stream>>>(h_in, w_he ? he_w : he_w, he_b, hB, N, 64);
  embed_kernel<<<2048, 256, 0, stream>>>(p_in, pe_w, pe_b, pB, N, 16);
  embed_kernel<<<4096, 256, 0, stream>>>(e_in, ee_w, ee_b, eB, E, 16);

  float* pOut = (float*)d_out + 256;
  const int gridE = (E + 255) / 256;  // 1563
  const int gridN = (N + 255) / 256;  // 196

  for (int l = 0; l < 4; ++l) {
    // h_msg = lin([h[s],p[s],h[r],p[r],e], hu_w) ; segment_sum by rec (fused atomics)
    hipMemsetAsync(aggF, 0, (size_t)N * 128 * 4, stream);
    gemm_mp<<<gridE, 256, 0, stream>>>(E, 5, 0x02211, 1,
        hB, pB, hB, pB, eB, send, rec,
        w_hu + (size_t)l * 128 * 640, hu_b + (size_t)l * 128, nullptr, aggF);
    f2b_kernel<<<2048, 256, 0, stream>>>(aggF, aggB, N * 128 / 4);
    // h = lin([h, h_msg_agg], hagg_w)   (in-place, row-wise safe)
    gemm_mp<<<gridN, 256, 0, stream>>>(N, 2, 0x00, 0,
        hB, aggB, nullptr, nullptr, nullptr, nullptr, nullptr,
        w_hg + (size_t)l * 128 * 256, hg_b + (size_t)l * 128, hB, nullptr);
    // e = lin([h_new[s], h_new[r], e], eu_w)   (in-place, row-wise safe)
    gemm_mp<<<gridE, 256, 0, stream>>>(E, 3, 0x021, 0,
        hB, hB, eB, nullptr, nullptr, send, rec,
        w_eu + (size_t)l * 128 * 384, eu_b + (size_t)l * 128, eB, nullptr);
    // p_msg = lin([p[s], p[r], e_new], pu_w) ; segment_sum by rec
    hipMemsetAsync(aggF, 0, (size_t)N * 128 * 4, stream);
    gemm_mp<<<gridE, 256, 0, stream>>>(E, 3, 0x021, 1,
        pB, pB, eB, nullptr, nullptr, send, rec,
        w_pu + (size_t)l * 128 * 384, pu_b + (size_t)l * 128, nullptr, aggF);
    f2b_kernel<<<2048, 256, 0, stream>>>(aggF, aggB, N * 128 / 4);
    // p = lin([p, p_msg_agg], pagg_w) ; last layer also writes fp32 p to d_out
    gemm_mp<<<gridN, 256, 0, stream>>>(N, 2, 0x00, 0,
        pB, aggB, nullptr, nullptr, nullptr, nullptr, nullptr,
        w_pg + (size_t)l * 128 * 256, pg_b + (size_t)l * 128, pB,
        (l == 3) ? pOut : nullptr);
  }

  hipMemsetAsync(hep, 0, (size_t)G * 256 * 4, stream);
  readout_agg<<<(N + 127) / 128, 256, 0, stream>>>(hB, pB, batch, hep, N);
  mlp_kernel<<<G, 128, 0, stream>>>(hep, r1w, r1b, r2w, r2b, r3w, r3b, (float*)d_out);
}

// Round 2
// 2708.373 us; speedup vs baseline: 1.8439x; 1.8439x over previous
//
#include <hip/hip_runtime.h>

typedef __attribute__((ext_vector_type(8))) short bf16x8;
typedef __attribute__((ext_vector_type(4))) float f32x4;
typedef __attribute__((ext_vector_type(4))) unsigned short us4;

__device__ __forceinline__ float b2f(unsigned short h) {
  union { unsigned int u; float f; } v; v.u = ((unsigned int)h) << 16; return v.f;
}
__device__ __forceinline__ unsigned short f2b(float f) {
  union { float f; unsigned int u; } v; v.f = f;
  unsigned int r = v.u + 0x7fffu + ((v.u >> 16) & 1u);
  return (unsigned short)(r >> 16);
}

// ---------------- fp32 -> bf16 bulk convert ----------------
__global__ void f2b_kernel(const float* __restrict__ in, unsigned short* __restrict__ out, int n4) {
  int i = blockIdx.x * blockDim.x + threadIdx.x;
  int stride = gridDim.x * blockDim.x;
  for (; i < n4; i += stride) {
    float4 v = reinterpret_cast<const float4*>(in)[i];
    us4 o;
    o.x = f2b(v.x); o.y = f2b(v.y); o.z = f2b(v.z); o.w = f2b(v.w);
    reinterpret_cast<us4*>(out)[i] = o;
  }
}

// ---------------- input embeddings: out[M,128] = in[M,K] @ w[128,K]^T + b ----------------
// w column hoisted to registers, 16-row input tiles staged in LDS, float4 broadcast reads.
template<int K>
__launch_bounds__(256)
__global__ void embed_fast(const float* __restrict__ in, const float* __restrict__ w,
                           const float* __restrict__ b, unsigned short* __restrict__ out, long M) {
  __shared__ float wT[K][128];
  __shared__ float xt[16 * K];
  const int tid = threadIdx.x;
  const int col = tid & 127;
  const int half = tid >> 7;
  for (int idx = tid; idx < 128 * K; idx += 256) {
    int c = idx / K, k = idx % K;  // coalesced global read; one-time LDS scatter
    wT[k][c] = w[idx];
  }
  __syncthreads();
  float wreg[K];
#pragma unroll
  for (int k = 0; k < K; ++k) wreg[k] = wT[k][col];
  const float bcol = b[col];

  for (long r0 = (long)blockIdx.x * 16; r0 < M; r0 += (long)gridDim.x * 16) {
    __syncthreads();  // WAR: previous iteration's xt reads done
    const float4* src4 = reinterpret_cast<const float4*>(in + r0 * K);
    const int n4 = 16 * K / 4;
    if (r0 + 16 <= M) {
      for (int i = tid; i < n4; i += 256)
        reinterpret_cast<float4*>(xt)[i] = src4[i];
    } else {
      int rem = (int)((M - r0) * K) / 4;
      for (int i = tid; i < n4; i += 256) {
        float4 z = {0.f, 0.f, 0.f, 0.f};
        reinterpret_cast<float4*>(xt)[i] = (i < rem) ? src4[i] : z;
      }
    }
    __syncthreads();
#pragma unroll
    for (int rr = 0; rr < 8; ++rr) {
      long row = r0 + half * 8 + rr;
      if (row >= M) break;
      const float* xr = &xt[(half * 8 + rr) * K];
      float acc = bcol;
#pragma unroll
      for (int k4 = 0; k4 < K / 4; ++k4) {
        float4 xv = reinterpret_cast<const float4*>(xr)[k4];
        acc += xv.x * wreg[k4 * 4] + xv.y * wreg[k4 * 4 + 1] +
               xv.z * wreg[k4 * 4 + 2] + xv.w * wreg[k4 * 4 + 3];
      }
      out[row * 128 + col] = f2b(acc);
    }
  }
}

// ---------------- main MFMA gather-GEMM ----------------
// X[M, nsrc*128] implicit: source si supplies k in [si*128,(si+1)*128),
// row index per source: kind 0 = direct row, 1 = send[row], 2 = rec[row].
// W: bf16 [128][nsrc*128] row-major (out-major, _lin's w layout).
// scatter=1: atomicAdd (acc+bias) into outF[rec[row]*128+col]
// scatter=0: write bf16 to outB[row], plus fp32 to outF if non-null.
__launch_bounds__(256, 2)
__global__ void gemm_mp(int M, int nsrc, int kinds, int scatter,
                        const unsigned short* __restrict__ sp0, const unsigned short* __restrict__ sp1,
                        const unsigned short* __restrict__ sp2, const unsigned short* __restrict__ sp3,
                        const unsigned short* __restrict__ sp4,
                        const int* __restrict__ send, const int* __restrict__ rec,
                        const unsigned short* __restrict__ Wb, const float* __restrict__ bias,
                        unsigned short* __restrict__ outB, float* __restrict__ outF) {
  __shared__ __align__(16) unsigned short ldsW[8 * 64 * 8];  // 8KB, fragment order [ntile][lane][8]
  const int tid = threadIdx.x;
  const int wid = tid >> 6, lane = tid & 63;
  const int K = nsrc * 128;
  const long rowBase = (long)blockIdx.x * 256 + wid * 64;
  const int lq = lane >> 4;  // 0..3
  const int lr = lane & 15;  // 0..15

  int rowD[4], idxS[4], idxR[4];
#pragma unroll
  for (int am = 0; am < 4; ++am) {
    long e = rowBase + am * 16 + lr;
    if (e >= M) e = M - 1;
    rowD[am] = (int)e;
    idxS[am] = send ? send[e] : (int)e;
    idxR[am] = rec ? rec[e] : (int)e;
  }

  f32x4 acc[4][8];
#pragma unroll
  for (int i = 0; i < 4; ++i)
#pragma unroll
    for (int j = 0; j < 8; ++j) acc[i][j] = 0.f;

  for (int si = 0; si < nsrc; ++si) {
    const unsigned short* sp = (si == 0) ? sp0 : (si == 1) ? sp1 : (si == 2) ? sp2 : (si == 3) ? sp3 : sp4;
    const int kd = (kinds >> (si * 4)) & 15;
#pragma unroll
    for (int sub = 0; sub < 4; ++sub) {
      const int k0 = si * 128 + sub * 32;
      __syncthreads();  // protect previous iteration's LDS reads (WAR)
      // stage W chunk [32k x 128n] into LDS in b-fragment order
#pragma unroll
      for (int it = 0; it < 2; ++it) {
        int idx = tid + it * 256;
        int t = idx >> 6, l = idx & 63;
        int n = t * 16 + (l & 15);
        int kk = k0 + ((l >> 4) * 8);
        *reinterpret_cast<bf16x8*>(&ldsW[idx * 8]) =
            *reinterpret_cast<const bf16x8*>(&Wb[(long)n * K + kk]);
      }
      __syncthreads();
      const int koff = sub * 32 + lq * 8;  // within source's 128-wide row
      bf16x8 a[4];
#pragma unroll
      for (int am = 0; am < 4; ++am) {
        int ridx = (kd == 0) ? rowD[am] : (kd == 1) ? idxS[am] : idxR[am];
        a[am] = *reinterpret_cast<const bf16x8*>(&sp[(long)ridx * 128 + koff]);
      }
#pragma unroll
      for (int n = 0; n < 8; ++n) {
        bf16x8 b = *reinterpret_cast<const bf16x8*>(&ldsW[(n * 64 + lane) * 8]);
#pragma unroll
        for (int am = 0; am < 4; ++am)
          acc[am][n] = __builtin_amdgcn_mfma_f32_16x16x32_bf16(a[am], b, acc[am][n], 0, 0, 0);
      }
    }
  }

  float bv[8];
#pragma unroll
  for (int n = 0; n < 8; ++n) bv[n] = bias[n * 16 + lr];

  // C layout (16x16x32 bf16): col = lane&15, row = (lane>>4)*4 + reg
  if (scatter) {
#pragma unroll
    for (int am = 0; am < 4; ++am) {
#pragma unroll
      for (int r = 0; r < 4; ++r) {
        long e = rowBase + am * 16 + lq * 4 + r;
        if (e < M) {
          int node = rec[e];
          float* dst = outF + (long)node * 128 + lr;
#pragma unroll
          for (int n = 0; n < 8; ++n) unsafeAtomicAdd(dst + n * 16, acc[am][n][r] + bv[n]);
        }
      }
    }
  } else {
#pragma unroll
    for (int am = 0; am < 4; ++am) {
#pragma unroll
      for (int r = 0; r < 4; ++r) {
        long row = rowBase + am * 16 + lq * 4 + r;
        if (row < M) {
#pragma unroll
          for (int n = 0; n < 8; ++n) {
            float v = acc[am][n][r] + bv[n];
            outB[row * 128 + n * 16 + lr] = f2b(v);
            if (outF) outF[row * 128 + n * 16 + lr] = v;
          }
        }
      }
    }
  }
}

// ---------------- per-graph aggregation (batch is sorted) ----------------
__global__ void readout_agg(const unsigned short* __restrict__ h, const unsigned short* __restrict__ p,
                            const int* __restrict__ batch, float* __restrict__ hep, int N) {
  int col = threadIdx.x & 127;
  int which = threadIdx.x >> 7;  // 0 -> h part, 1 -> p part
  const unsigned short* src = which ? p : h;
  int n0 = blockIdx.x * 128;
  int n1 = n0 + 128; if (n1 > N) n1 = N;
  float sum = 0.f; int curg = -1;
  for (int n = n0; n < n1; ++n) {
    int g = batch[n];
    if (g != curg) {
      if (curg >= 0) unsafeAtomicAdd(&hep[(long)curg * 256 + which * 128 + col], sum);
      curg = g; sum = 0.f;
    }
    sum += b2f(src[(long)n * 128 + col]);
  }
  if (curg >= 0) unsafeAtomicAdd(&hep[(long)curg * 256 + which * 128 + col], sum);
}

// ---------------- readout MLP: one block per graph ----------------
__global__ void mlp_kernel(const float* __restrict__ hep,
                           const float* __restrict__ r1w, const float* __restrict__ r1b,
                           const float* __restrict__ r2w, const float* __restrict__ r2b,
                           const float* __restrict__ r3w, const float* __restrict__ r3b,
                           float* __restrict__ out) {
  int g = blockIdx.x, t = threadIdx.x;  // 128 threads
  __shared__ float x[256];
  __shared__ float y[128];
  __shared__ float z[64];
  x[t] = hep[(long)g * 256 + t];
  x[t + 128] = hep[(long)g * 256 + 128 + t];
  __syncthreads();
  float s = r1b[t];
  for (int k = 0; k < 256; ++k) s += r1w[t * 256 + k] * x[k];
  y[t] = fmaxf(s, 0.f);
  __syncthreads();
  if (t < 64) {
    float s2 = r2b[t];
    for (int k = 0; k < 128; ++k) s2 += r2w[t * 128 + k] * y[k];
    z[t] = fmaxf(s2, 0.f);
  }
  __syncthreads();
  if (t == 0) {
    float s3 = r3b[0];
    for (int k = 0; k < 64; ++k) s3 += r3w[k] * z[k];
    out[g] = s3;
  }
}

extern "C" void kernel_launch(void* const* d_in, const int* in_sizes, int n_in,
                              void* d_out, int out_size, void* d_ws, size_t ws_size,
                              hipStream_t stream) {
  const float* h_in = (const float*)d_in[0];
  const float* e_in = (const float*)d_in[1];
  const float* p_in = (const float*)d_in[2];
  const int* ei = (const int*)d_in[3];
  const int* batch = (const int*)d_in[4];
  const float* he_w = (const float*)d_in[5];  const float* he_b = (const float*)d_in[6];
  const float* ee_w = (const float*)d_in[7];  const float* ee_b = (const float*)d_in[8];
  const float* pe_w = (const float*)d_in[9];  const float* pe_b = (const float*)d_in[10];
  const float* hu_w = (const float*)d_in[11]; const float* hu_b = (const float*)d_in[12];
  const float* eu_w = (const float*)d_in[13]; const float* eu_b = (const float*)d_in[14];
  const float* pu_w = (const float*)d_in[15]; const float* pu_b = (const float*)d_in[16];
  const float* hg_w = (const float*)d_in[17]; const float* hg_b = (const float*)d_in[18];
  const float* pg_w = (const float*)d_in[19]; const float* pg_b = (const float*)d_in[20];
  const float* r1w = (const float*)d_in[21];  const float* r1b = (const float*)d_in[22];
  const float* r2w = (const float*)d_in[23];  const float* r2b = (const float*)d_in[24];
  const float* r3w = (const float*)d_in[25];  const float* r3b = (const float*)d_in[26];

  const int N = 50000, E = 400000, G = 256;
  const int* send = ei;
  const int* rec = ei + E;

  char* ws = (char*)d_ws;
  size_t off = 0;
  auto alloc = [&](size_t bytes) {
    void* pp = ws + off;
    off += (bytes + 255) & ~(size_t)255;
    return pp;
  };
  unsigned short* hB = (unsigned short*)alloc((size_t)N * 128 * 2);
  unsigned short* pB = (unsigned short*)alloc((size_t)N * 128 * 2);
  unsigned short* eB = (unsigned short*)alloc((size_t)E * 128 * 2);
  float* aggF = (float*)alloc((size_t)N * 128 * 4);
  unsigned short* aggB = (unsigned short*)alloc((size_t)N * 128 * 2);
  float* hep = (float*)alloc((size_t)G * 256 * 4);
  unsigned short* w_hu = (unsigned short*)alloc((size_t)4 * 128 * 640 * 2);
  unsigned short* w_eu = (unsigned short*)alloc((size_t)4 * 128 * 384 * 2);
  unsigned short* w_pu = (unsigned short*)alloc((size_t)4 * 128 * 384 * 2);
  unsigned short* w_hg = (unsigned short*)alloc((size_t)4 * 128 * 256 * 2);
  unsigned short* w_pg = (unsigned short*)alloc((size_t)4 * 128 * 256 * 2);
  (void)ws_size; (void)n_in; (void)in_sizes; (void)out_size;

  auto conv = [&](const float* s, unsigned short* dst, int n) {
    int n4 = n / 4;
    int grid = (n4 + 255) / 256; if (grid > 2048) grid = 2048;
    f2b_kernel<<<grid, 256, 0, stream>>>(s, dst, n4);
  };
  conv(hu_w, w_hu, 4 * 128 * 640);
  conv(eu_w, w_eu, 4 * 128 * 384);
  conv(pu_w, w_pu, 4 * 128 * 384);
  conv(hg_w, w_hg, 4 * 128 * 256);
  conv(pg_w, w_pg, 4 * 128 * 256);

  embed_fast<64><<<3125, 256, 0, stream>>>(h_in, he_w, he_b, hB, N);
  embed_fast<16><<<3125, 256, 0, stream>>>(p_in, pe_w, pe_b, pB, N);
  embed_fast<16><<<4096, 256, 0, stream>>>(e_in, ee_w, ee_b, eB, E);

  float* pOut = (float*)d_out + 256;
  const int gridE = (E + 255) / 256;  // 1563
  const int gridN = (N + 255) / 256;  // 196

  for (int l = 0; l < 4; ++l) {
    // h_msg = lin([h[s],p[s],h[r],p[r],e], hu_w) ; segment_sum by rec (fused atomics)
    hipMemsetAsync(aggF, 0, (size_t)N * 128 * 4, stream);
    gemm_mp<<<gridE, 256, 0, stream>>>(E, 5, 0x02211, 1,
        hB, pB, hB, pB, eB, send, rec,
        w_hu + (size_t)l * 128 * 640, hu_b + (size_t)l * 128, nullptr, aggF);
    f2b_kernel<<<2048, 256, 0, stream>>>(aggF, aggB, N * 128 / 4);
    // h = lin([h, h_msg_agg], hagg_w)   (in-place, row-wise safe)
    gemm_mp<<<gridN, 256, 0, stream>>>(N, 2, 0x00, 0,
        hB, aggB, nullptr, nullptr, nullptr, nullptr, nullptr,
        w_hg + (size_t)l * 128 * 256, hg_b + (size_t)l * 128, hB, nullptr);
    // e = lin([h_new[s], h_new[r], e], eu_w)   (in-place, row-wise safe)
    gemm_mp<<<gridE, 256, 0, stream>>>(E, 3, 0x021, 0,
        hB, hB, eB, nullptr, nullptr, send, rec,
        w_eu + (size_t)l * 128 * 384, eu_b + (size_t)l * 128, eB, nullptr);
    // p_msg = lin([p[s], p[r], e_new], pu_w) ; segment_sum by rec
    hipMemsetAsync(aggF, 0, (size_t)N * 128 * 4, stream);
    gemm_mp<<<gridE, 256, 0, stream>>>(E, 3, 0x021, 1,
        pB, pB, eB, nullptr, nullptr, send, rec,
        w_pu + (size_t)l * 128 * 384, pu_b + (size_t)l * 128, nullptr, aggF);
    f2b_kernel<<<2048, 256, 0, stream>>>(aggF, aggB, N * 128 / 4);
    // p = lin([p, p_msg_agg], pagg_w) ; last layer also writes fp32 p to d_out
    gemm_mp<<<gridN, 256, 0, stream>>>(N, 2, 0x00, 0,
        pB, aggB, nullptr, nullptr, nullptr, nullptr, nullptr,
        w_pg + (size_t)l * 128 * 256, pg_b + (size_t)l * 128, pB,
        (l == 3) ? pOut : nullptr);
  }

  hipMemsetAsync(hep, 0, (size_t)G * 256 * 4, stream);
  readout_agg<<<(N + 127) / 128, 256, 0, stream>>>(hB, pB, batch, hep, N);
  mlp_kernel<<<G, 128, 0, stream>>>(hep, r1w, r1b, r2w, r2b, r3w, r3b, (float*)d_out);
}